// Round 5
// baseline (328.424 us; speedup 1.0000x reference)
//
#include <hip/hip_runtime.h>
#include <hip/hip_bf16.h>
#include <math.h>

typedef __hip_bfloat16 bf16;
typedef __attribute__((ext_vector_type(8))) short s8v;   // 8 bf16 (4 VGPRs)
typedef __attribute__((ext_vector_type(4))) float f4v;

#define B_   16
#define T_   1024
#define C_   512
#define M_   (B_*T_)      // 16384
#define NW_  4
#define KWIN 25
#define TCHUNK 16
#define NCHUNK (T_/TCHUNK)   // 64

__device__ __forceinline__ float b2f(bf16 v){ return __bfloat162float(v); }
__device__ __forceinline__ bf16  f2b(float v){ return __float2bfloat16(v); }

// async global->LDS, 16B per lane; LDS dest = wave-uniform base + lane*16
__device__ __forceinline__ void gload16(const bf16* g, bf16* l) {
    __builtin_amdgcn_global_load_lds(
        (const __attribute__((address_space(1))) void*)g,
        (__attribute__((address_space(3))) void*)l, 16, 0, 0);
}

// ---------------------------------------------------------------- K0: repack wavelet + amp weights (transposed bf16)
__global__ __launch_bounds__(256) void repack_kernel(
    const float* __restrict__ wav,    // [NW][C][C] (w,c,o)
    const float* __restrict__ ampw,   // [C][C]     (c,o)
    bf16* __restrict__ WWT,           // [512][2048] : WWT[o][w*512+c]
    bf16* __restrict__ AWT)           // [512][512]  : AWT[o][c]
{
    int id = blockIdx.x * 256 + threadIdx.x;
    if (id < 512 * 2048) {
        int o = id >> 11, k = id & 2047;
        int w = k >> 9, c2 = k & 511;
        WWT[id] = f2b(wav[(w * 512 + c2) * 512 + o]);
    }
    if (id < 512 * 512) {
        int o = id >> 9, c = id & 511;
        AWT[id] = f2b(ampw[c * 512 + o]);
    }
}

// ---------------------------------------------------------------- K0b: cheby -> power-basis panel CCT[o][p*512+c] + bias0[o]
// trend_out = bias0 + x*(W1-3W3) + x^2*(2W2) + x^3*(4W3), bias0 = sum_c (W0-W2)
__global__ __launch_bounds__(64) void repack_cct_kernel(
    const float* __restrict__ cheby,  // [C][C][4] (c,o,d)
    bf16* __restrict__ CCT,           // [512][1536]
    float* __restrict__ bias0)        // [512]
{
    const int o = blockIdx.x, l = threadIdx.x;
    float bsum = 0.f;
    #pragma unroll
    for (int j = 0; j < 8; ++j) {
        int c = l + j * 64;
        float4 w = *(const float4*)&cheby[(size_t)c * 2048 + o * 4];
        bsum += w.x - w.z;
        CCT[(size_t)o * 1536 + c]        = f2b(w.y - 3.f * w.w);
        CCT[(size_t)o * 1536 + 512 + c]  = f2b(2.f * w.z);
        CCT[(size_t)o * 1536 + 1024 + c] = f2b(4.f * w.w);
    }
    #pragma unroll
    for (int off = 32; off >= 1; off >>= 1) bsum += __shfl_down(bsum, off);
    if (l == 0) bias0[o] = bsum;
}

// ---------------------------------------------------------------- K0c: LDS-tiled transpose w1[1024][512] -> w1T[512][1024]
__global__ __launch_bounds__(256) void transpose_w1_kernel(
    const float* __restrict__ w1, float* __restrict__ w1t)
{
    __shared__ float tile[32][33];
    const int bo = blockIdx.x, bj = blockIdx.y;
    const int tx = threadIdx.x & 31, ty = threadIdx.x >> 5;
    #pragma unroll
    for (int r = 0; r < 32; r += 8)
        tile[ty + r][tx] = w1[(size_t)(bj * 32 + ty + r) * 512 + bo * 32 + tx];
    __syncthreads();
    #pragma unroll
    for (int r = 0; r < 32; r += 8)
        w1t[(size_t)(bo * 32 + ty + r) * 1024 + bj * 32 + tx] = tile[tx][ty + r];
}

// ---------------------------------------------------------------- K1: causal MA + dwconv3 x3 + pools (float2 per thread)
__global__ __launch_bounds__(256) void decomp_kernel(
    const float* __restrict__ x,
    const float* __restrict__ tcw, const float* __restrict__ tcb,
    const float* __restrict__ scw, const float* __restrict__ scb,
    const float* __restrict__ lcw, const float* __restrict__ lcb,
    bf16* __restrict__ xt, bf16* __restrict__ sctx,
    float* __restrict__ slope_part, float* __restrict__ value_part)
{
    const int c     = threadIdx.x * 2;          // channel pair
    const int chunk = blockIdx.x;               // 64 chunks
    const int b     = blockIdx.y;               // 16
    const int t0    = chunk * TCHUNK;
    const float* xb = x + (size_t)b * T_ * C_ + c;

    auto X = [&](int i) -> float2 {
        i = i < 0 ? 0 : (i > T_ - 1 ? T_ - 1 : i);
        return *(const float2*)&xb[(size_t)i * C_];
    };

    float w0t[2], w1t_[2], w2t[2], bt[2], w0s[2], w1s[2], w2s[2], bs[2], w0l[2], w1l[2], w2l[2], bl[2];
    #pragma unroll
    for (int e = 0; e < 2; ++e) {
        w0t[e]=tcw[(c+e)*3+0]; w1t_[e]=tcw[(c+e)*3+1]; w2t[e]=tcw[(c+e)*3+2]; bt[e]=tcb[c+e];
        w0s[e]=scw[(c+e)*3+0]; w1s[e]=scw[(c+e)*3+1]; w2s[e]=scw[(c+e)*3+2]; bs[e]=scb[c+e];
        w0l[e]=lcw[(c+e)*3+0]; w1l[e]=lcw[(c+e)*3+1]; w2l[e]=lcw[(c+e)*3+2]; bl[e]=lcb[c+e];
    }

    const float inv = 1.f / KWIN;
    int j0 = (t0 > 0) ? (t0 - 1) : 0;
    float S[2] = {0.f, 0.f};
    #pragma unroll
    for (int i = j0 - (KWIN - 1); i <= j0; ++i) { float2 v = X(i); S[0] += v.x; S[1] += v.y; }
    float trm[2], tr0[2], xm[2], x0v[2], sAcc[2] = {0.f,0.f}, vAcc[2] = {0.f,0.f};
    trm[0] = S[0] * inv; trm[1] = S[1] * inv;
    if (t0 > 0) {
        float2 a = X(t0), d = X(t0 - KWIN);
        S[0] += a.x - d.x; S[1] += a.y - d.y;
        tr0[0] = S[0] * inv; tr0[1] = S[1] * inv;
    } else { tr0[0] = trm[0]; tr0[1] = trm[1]; }
    { float2 v = X(t0 - 1); xm[0] = v.x; xm[1] = v.y; }
    { float2 v = X(t0);     x0v[0] = v.x; x0v[1] = v.y; }

    #pragma unroll
    for (int t = t0; t < t0 + TCHUNK; ++t) {
        float trp[2], xp[2];
        int tn = t + 1;
        if (tn <= T_ - 1) {
            float2 a = X(tn), d = X(tn - KWIN);
            S[0] += a.x - d.x; S[1] += a.y - d.y;
            trp[0] = S[0] * inv; trp[1] = S[1] * inv;
            xp[0] = a.x; xp[1] = a.y;
        } else {
            trp[0] = tr0[0]; trp[1] = tr0[1];
            xp[0] = x0v[0];  xp[1] = x0v[1];
        }
        union { bf16 h[2]; unsigned u; } uxt, usc;
        #pragma unroll
        for (int e = 0; e < 2; ++e) {
            float tctx = w0t[e]*trm[e] + w1t_[e]*tr0[e] + w2t[e]*trp[e] + bt[e];
            float sm = xm[e]-trm[e], s0 = x0v[e]-tr0[e], sp = xp[e]-trp[e];
            float sv = w0s[e]*sm + w1s[e]*s0 + w2s[e]*sp + bs[e];
            float sl = w0l[e]*trm[e] + w1l[e]*tr0[e] + w2l[e]*trp[e] + bl[e];
            sAcc[e] += sl; vAcc[e] += tr0[e];
            uxt.h[e] = f2b(tanhf(tctx)); usc.h[e] = f2b(sv);
            trm[e] = tr0[e]; tr0[e] = trp[e]; xm[e] = x0v[e]; x0v[e] = xp[e];
        }
        size_t oidx = ((size_t)b * T_ + t) * C_ + c;
        *(unsigned*)&xt[oidx]   = uxt.u;
        *(unsigned*)&sctx[oidx] = usc.u;
    }
    int pidx = (chunk * B_ + b) * C_ + c;
    *(float2*)&slope_part[pidx] = make_float2(sAcc[0], sAcc[1]);
    *(float2*)&value_part[pidx] = make_float2(vAcc[0], vAcc[1]);
}

// ---------------------------------------------------------------- K2a: pool reduce -> pc[16][1024]
__global__ __launch_bounds__(256) void pool_kernel(
    const float* __restrict__ slope_part, const float* __restrict__ value_part,
    float* __restrict__ pc)
{
    int idx = blockIdx.x * 256 + threadIdx.x;   // 16384
    int b = idx >> 10, j = idx & 1023;
    int c = j & 511;
    const float* src = (j < 512) ? slope_part : value_part;
    float s = 0.f;
    #pragma unroll 8
    for (int ch = 0; ch < NCHUNK; ++ch) s += src[(ch * B_ + b) * C_ + c];
    pc[idx] = s * (1.f / T_);
}

// ---------------------------------------------------------------- K2b: h = silu(pc @ w1 + b1); 1 block per o
__global__ __launch_bounds__(256) void hyper1_kernel(
    const float* __restrict__ pc, const float* __restrict__ w1t,
    const float* __restrict__ b1, float* __restrict__ h)
{
    const int o = blockIdx.x, t = threadIdx.x;
    const float4 w = *(const float4*)&w1t[(size_t)o * 1024 + t * 4];
    float acc[16];
    #pragma unroll
    for (int b = 0; b < 16; ++b) {
        float4 p = *(const float4*)&pc[(size_t)b * 1024 + t * 4];
        acc[b] = w.x * p.x + w.y * p.y + w.z * p.z + w.w * p.w;
    }
    #pragma unroll
    for (int off = 32; off >= 1; off >>= 1)
        #pragma unroll
        for (int b = 0; b < 16; ++b) acc[b] += __shfl_down(acc[b], off);
    __shared__ float red[4][16];
    int lane = t & 63, wv = t >> 6;
    if (lane == 0)
        #pragma unroll
        for (int b = 0; b < 16; ++b) red[wv][b] = acc[b];
    __syncthreads();
    if (t < 16) {
        float s = red[0][t] + red[1][t] + red[2][t] + red[3][t] + b1[o];
        h[(size_t)t * 512 + o] = s / (1.f + expf(-s));
    }
}

// ---------------------------------------------------------------- K2c: params -> dyn_a, dyn_b
__global__ __launch_bounds__(128) void hyper2_kernel(
    const float* __restrict__ h, const float* __restrict__ w2,
    const float* __restrict__ b2, float* __restrict__ dyn_a, float* __restrict__ dyn_b)
{
    __shared__ float pp[16][8];
    const int t = threadIdx.x, b = t >> 3, o = t & 7;
    float acc = b2[o];
    #pragma unroll 4
    for (int j = 0; j < 512; ++j) acc += h[(size_t)b * 512 + j] * w2[j * 8 + o];
    pp[b][o] = acc;
    __syncthreads();
    if (t < 64) {
        int bb = t >> 2, w = t & 3;
        float pa = pp[bb][2 * w], pb = pp[bb][2 * w + 1];
        float sp = fmaxf(pa, 0.f) + log1pf(expf(-fabsf(pa)));
        dyn_a[bb * NW_ + w] = sp + 0.01f;
        dyn_b[bb * NW_ + w] = (1.f / (1.f + expf(-pb))) * (float)T_;
    }
}

// ---------------------------------------------------------------- K2d: psi[m][w] Ricker wavelet
__global__ __launch_bounds__(256) void psi_kernel(
    const float* __restrict__ dyn_a, const float* __restrict__ dyn_b,
    float* __restrict__ psi)
{
    int idx = blockIdx.x * 256 + threadIdx.x;
    int w = idx & 3, m = idx >> 2;
    int b = m >> 10, t = m & 1023;
    float z = ((float)t - dyn_b[b * 4 + w]) / dyn_a[b * 4 + w];
    float z2 = z * z;
    psi[idx] = (1.f - z2) * expf(-0.5f * z2);
}

// ---------------------------------------------------------------- Fused big GEMM (blockIdx.z: 0=cheb K=1536, 1=wavelet K=2048)
// A kept in registers (global loads + in-reg transform). B staged via
// global_load_lds into linear [128][64] LDS with XOR slot swizzle.
__global__ __launch_bounds__(256, 3) void gemm_big_kernel(
    const bf16* __restrict__ xtg,  const bf16* __restrict__ sctxg,
    const bf16* __restrict__ CCT,  const bf16* __restrict__ WWT,
    const float* __restrict__ psi, const float* __restrict__ bias0,
    bf16* __restrict__ tout, bf16* __restrict__ sout)
{
    __shared__ bf16 lB[128 * 64];   // 16 KB

    const int mode = blockIdx.z;
    const bf16* Aact = mode ? sctxg : xtg;
    const bf16* BTm  = mode ? WWT : CCT;
    const int   K    = mode ? 2048 : 1536;
    bf16*       Cmat = mode ? sout : tout;

    const int tid = threadIdx.x;
    const int m0 = blockIdx.y * 128, n0 = blockIdx.x * 128;
    const int lane = tid & 63, wv = tid >> 6;
    const int wr = wv >> 1, wc = wv & 1;
    const int r16 = lane & 15, g = lane >> 4;

    // B staging geometry: wave wv covers rows [wv*32, wv*32+32)
    const int srow = wv * 32 + (lane >> 3);   // +i2*8
    const int sslot = lane & 7;

    // A row pointers (lane-fixed rows), pre-offset by g*8
    const bf16* aptr[4];
    #pragma unroll
    for (int i = 0; i < 4; ++i)
        aptr[i] = Aact + (size_t)(m0 + wr * 64 + i * 16 + r16) * C_ + g * 8;

    float4 p4[4];
    if (mode == 1) {
        #pragma unroll
        for (int i = 0; i < 4; ++i)
            p4[i] = *(const float4*)&psi[(size_t)(m0 + wr * 64 + i * 16 + r16) * 4];
    }

    f4v acc[4][4];
    #pragma unroll
    for (int i = 0; i < 4; ++i)
        #pragma unroll
        for (int j = 0; j < 4; ++j) acc[i][j] = (f4v)0.f;

    const int nK = K >> 6;
    for (int kt = 0; kt < nK; ++kt) {
        const int k0 = kt << 6;
        const int wsel = k0 >> 9;   // power index (mode0) / wavelet (mode1)

        // ---- issue B tile loads (async, direct to LDS) ----
        #pragma unroll
        for (int i2 = 0; i2 < 4; ++i2) {
            int r = srow + i2 * 8;
            int ls = sslot ^ (r & 7);
            gload16(BTm + (size_t)(n0 + r) * K + k0 + ls * 8,
                    &lB[(wv * 32 + i2 * 8) * 64]);
        }

        // ---- A fragments: global loads + in-reg transform ----
        float sc[4];
        if (mode == 1) {
            #pragma unroll
            for (int i = 0; i < 4; ++i)
                sc[i] = wsel == 0 ? p4[i].x : wsel == 1 ? p4[i].y : wsel == 2 ? p4[i].z : p4[i].w;
        }
        s8v afr[2][4];
        #pragma unroll
        for (int ks = 0; ks < 2; ++ks) {
            const int kOff = (k0 + ks * 32) & 511;
            #pragma unroll
            for (int i = 0; i < 4; ++i) {
                s8v raw = *(const s8v*)(aptr[i] + kOff);
                if (mode == 0) {
                    if (wsel == 0) afr[ks][i] = raw;
                    else {
                        #pragma unroll
                        for (int e = 0; e < 8; ++e) {
                            float v = b2f(((const bf16*)&raw)[e]);
                            float vv = v * v;
                            ((bf16*)&afr[ks][i])[e] = f2b(wsel == 1 ? vv : vv * v);
                        }
                    }
                } else {
                    #pragma unroll
                    for (int e = 0; e < 8; ++e)
                        ((bf16*)&afr[ks][i])[e] = f2b(b2f(((const bf16*)&raw)[e]) * sc[i]);
                }
            }
        }
        __syncthreads();   // B tile resident (vmcnt drain) + all reads of prev tile done

        #pragma unroll
        for (int ks = 0; ks < 2; ++ks) {
            s8v bfr[4];
            #pragma unroll
            for (int j = 0; j < 4; ++j) {
                int brow = wc * 64 + j * 16 + r16;
                bfr[j] = *(const s8v*)((const char*)lB + brow * 128 + (((ks * 4 + g) ^ (brow & 7)) << 4));
            }
            #pragma unroll
            for (int i = 0; i < 4; ++i)
                #pragma unroll
                for (int j = 0; j < 4; ++j)
                    acc[i][j] = __builtin_amdgcn_mfma_f32_16x16x32_bf16(afr[ks][i], bfr[j], acc[i][j], 0, 0, 0);
        }
        __syncthreads();
    }

    // ---- C write (D: col=lane&15, row=(lane>>4)*4+r), + bias for mode0 ----
    float bb[4];
    #pragma unroll
    for (int j = 0; j < 4; ++j)
        bb[j] = (mode == 0) ? bias0[n0 + wc * 64 + j * 16 + r16] : 0.f;
    #pragma unroll
    for (int i = 0; i < 4; ++i)
        #pragma unroll
        for (int j = 0; j < 4; ++j)
            #pragma unroll
            for (int r = 0; r < 4; ++r) {
                int rr = m0 + wr * 64 + i * 16 + g * 4 + r;
                int cc = n0 + wc * 64 + j * 16 + r16;
                Cmat[(size_t)rr * 512 + cc] = f2b(acc[i][j][r] + bb[j]);
            }
}

// ---------------------------------------------------------------- GEMM2: ampin = tout @ AWT^T, K=512, both sides gload_lds
__global__ __launch_bounds__(256, 3) void gemm2_kernel(
    const bf16* __restrict__ Ag, const bf16* __restrict__ Bg,
    bf16* __restrict__ Cmat)
{
    __shared__ bf16 lA[128 * 64];
    __shared__ bf16 lB[128 * 64];

    const int tid = threadIdx.x;
    const int m0 = blockIdx.y * 128, n0 = blockIdx.x * 128;
    const int lane = tid & 63, wv = tid >> 6;
    const int wr = wv >> 1, wc = wv & 1;
    const int r16 = lane & 15, g = lane >> 4;
    const int srow = wv * 32 + (lane >> 3);
    const int sslot = lane & 7;

    f4v acc[4][4];
    #pragma unroll
    for (int i = 0; i < 4; ++i)
        #pragma unroll
        for (int j = 0; j < 4; ++j) acc[i][j] = (f4v)0.f;

    for (int kt = 0; kt < 8; ++kt) {
        const int k0 = kt << 6;
        #pragma unroll
        for (int i2 = 0; i2 < 4; ++i2) {
            int r = srow + i2 * 8;
            int ls = sslot ^ (r & 7);
            gload16(Ag + (size_t)(m0 + r) * 512 + k0 + ls * 8, &lA[(wv * 32 + i2 * 8) * 64]);
            gload16(Bg + (size_t)(n0 + r) * 512 + k0 + ls * 8, &lB[(wv * 32 + i2 * 8) * 64]);
        }
        __syncthreads();
        #pragma unroll
        for (int ks = 0; ks < 2; ++ks) {
            s8v afr[4], bfr[4];
            #pragma unroll
            for (int i = 0; i < 4; ++i) {
                int arow = wr * 64 + i * 16 + r16;
                afr[i] = *(const s8v*)((const char*)lA + arow * 128 + (((ks * 4 + g) ^ (arow & 7)) << 4));
            }
            #pragma unroll
            for (int j = 0; j < 4; ++j) {
                int brow = wc * 64 + j * 16 + r16;
                bfr[j] = *(const s8v*)((const char*)lB + brow * 128 + (((ks * 4 + g) ^ (brow & 7)) << 4));
            }
            #pragma unroll
            for (int i = 0; i < 4; ++i)
                #pragma unroll
                for (int j = 0; j < 4; ++j)
                    acc[i][j] = __builtin_amdgcn_mfma_f32_16x16x32_bf16(afr[i], bfr[j], acc[i][j], 0, 0, 0);
        }
        __syncthreads();
    }
    #pragma unroll
    for (int i = 0; i < 4; ++i)
        #pragma unroll
        for (int j = 0; j < 4; ++j)
            #pragma unroll
            for (int r = 0; r < 4; ++r) {
                int rr = m0 + wr * 64 + i * 16 + g * 4 + r;
                int cc = n0 + wc * 64 + j * 16 + r16;
                Cmat[(size_t)rr * 512 + cc] = f2b(acc[i][j][r]);
            }
}

// ---------------------------------------------------------------- K6: amp gate + residual + LayerNorm
__global__ __launch_bounds__(256) void epilogue_kernel(
    const float* __restrict__ x,   const bf16* __restrict__ tout,
    const bf16* __restrict__ sout, const bf16* __restrict__ ampin,
    const float* __restrict__ ampb, const float* __restrict__ gamma,
    const float* __restrict__ beta, float* __restrict__ out)
{
    __shared__ float red[8];
    const int m = blockIdx.x, tid = threadIdx.x;
    const size_t base = (size_t)m * 512;

    float y[2];
    #pragma unroll
    for (int q = 0; q < 2; ++q) {
        int c = tid + q * 256;
        float to = b2f(tout[base + c]);
        float so = b2f(sout[base + c]);
        float ai = b2f(ampin[base + c]) + ampb[c];
        float amp = 2.f / (1.f + expf(-ai));
        y[q] = to + so * amp + x[base + c];
    }
    float s = y[0] + y[1], sq = y[0] * y[0] + y[1] * y[1];
    #pragma unroll
    for (int off = 32; off >= 1; off >>= 1) {
        s  += __shfl_down(s, off);
        sq += __shfl_down(sq, off);
    }
    int lane = tid & 63, wv = tid >> 6;
    if (lane == 0) { red[wv * 2] = s; red[wv * 2 + 1] = sq; }
    __syncthreads();
    if (tid == 0) {
        float ts = 0.f, tq = 0.f;
        #pragma unroll
        for (int i = 0; i < 4; ++i) { ts += red[i * 2]; tq += red[i * 2 + 1]; }
        red[0] = ts; red[1] = tq;
    }
    __syncthreads();
    float mu  = red[0] * (1.f / 512.f);
    float var = red[1] * (1.f / 512.f) - mu * mu;
    float rstd = rsqrtf(var + 1e-5f);
    #pragma unroll
    for (int q = 0; q < 2; ++q) {
        int c = tid + q * 256;
        out[base + c] = (y[q] - mu) * rstd * gamma[c] + beta[c];
    }
}

// ----------------------------------------------------------------
extern "C" void kernel_launch(void* const* d_in, const int* in_sizes, int n_in,
                              void* d_out, int out_size, void* d_ws, size_t ws_size,
                              hipStream_t stream)
{
    const float* x     = (const float*)d_in[0];
    const float* tcw   = (const float*)d_in[1];
    const float* tcb   = (const float*)d_in[2];
    const float* scw   = (const float*)d_in[3];
    const float* scb   = (const float*)d_in[4];
    const float* lcw   = (const float*)d_in[5];
    const float* lcb   = (const float*)d_in[6];
    const float* cheby = (const float*)d_in[7];
    const float* hw1   = (const float*)d_in[8];
    const float* hb1   = (const float*)d_in[9];
    const float* hw2   = (const float*)d_in[10];
    const float* hb2   = (const float*)d_in[11];
    const float* ampw  = (const float*)d_in[12];
    const float* ampb  = (const float*)d_in[13];
    const float* wav   = (const float*)d_in[14];
    const float* lng   = (const float*)d_in[15];
    const float* lnb   = (const float*)d_in[16];
    float* out = (float*)d_out;

    char* ws = (char*)d_ws;
    size_t off = 0;
    auto alloc = [&](size_t bytes) -> char* {
        char* p = ws + off;
        off += (bytes + 255) & ~(size_t)255;
        return p;
    };
    bf16*  xt         = (bf16*)alloc((size_t)M_ * 512 * 2);
    bf16*  sctx       = (bf16*)alloc((size_t)M_ * 512 * 2);
    bf16*  tout       = (bf16*)alloc((size_t)M_ * 512 * 2);
    bf16*  sout       = (bf16*)alloc((size_t)M_ * 512 * 2);
    bf16*  ampin      = (bf16*)alloc((size_t)M_ * 512 * 2);
    bf16*  CCT        = (bf16*)alloc((size_t)512 * 1536 * 2);
    bf16*  WWT        = (bf16*)alloc((size_t)512 * 2048 * 2);
    bf16*  AWT        = (bf16*)alloc((size_t)512 * 512 * 2);
    float* W1T        = (float*)alloc((size_t)512 * 1024 * 4);
    float* bias0      = (float*)alloc(512 * 4);
    float* slope_part = (float*)alloc((size_t)NCHUNK * B_ * C_ * 4);
    float* value_part = (float*)alloc((size_t)NCHUNK * B_ * C_ * 4);
    float* pc         = (float*)alloc(B_ * 1024 * 4);
    float* hbuf       = (float*)alloc(B_ * C_ * 4);
    float* dyn_a      = (float*)alloc(B_ * NW_ * 4);
    float* dyn_b      = (float*)alloc(B_ * NW_ * 4);
    float* psi        = (float*)alloc((size_t)M_ * NW_ * 4);

    repack_kernel<<<4096, 256, 0, stream>>>(wav, ampw, WWT, AWT);
    repack_cct_kernel<<<512, 64, 0, stream>>>(cheby, CCT, bias0);
    transpose_w1_kernel<<<dim3(16, 32), 256, 0, stream>>>(hw1, W1T);
    decomp_kernel<<<dim3(NCHUNK, B_), 256, 0, stream>>>(x, tcw, tcb, scw, scb, lcw, lcb,
                                                        xt, sctx, slope_part, value_part);
    pool_kernel<<<64, 256, 0, stream>>>(slope_part, value_part, pc);
    hyper1_kernel<<<512, 256, 0, stream>>>(pc, W1T, hb1, hbuf);
    hyper2_kernel<<<1, 128, 0, stream>>>(hbuf, hw2, hb2, dyn_a, dyn_b);
    psi_kernel<<<256, 256, 0, stream>>>(dyn_a, dyn_b, psi);
    gemm_big_kernel<<<dim3(4, 128, 2), 256, 0, stream>>>(xt, sctx, CCT, WWT, psi, bias0, tout, sout);
    gemm2_kernel<<<dim3(4, 128), 256, 0, stream>>>(tout, AWT, ampin);
    epilogue_kernel<<<16384, 256, 0, stream>>>(x, tout, sout, ampin, ampb, lng, lnb, out);
}

// Round 6
// 213.270 us; speedup vs baseline: 1.5399x; 1.5399x over previous
//
#include <hip/hip_runtime.h>
#include <hip/hip_bf16.h>
#include <math.h>

typedef __hip_bfloat16 bf16;
typedef __attribute__((ext_vector_type(8))) short s8v;   // 8 bf16 (4 VGPRs)
typedef __attribute__((ext_vector_type(4))) float f4v;

#define B_   16
#define T_   1024
#define C_   512
#define M_   (B_*T_)      // 16384
#define NW_  4
#define KWIN 25
#define TCHUNK 16
#define NCHUNK (T_/TCHUNK)   // 64

__device__ __forceinline__ float b2f(bf16 v){ return __bfloat162float(v); }
__device__ __forceinline__ bf16  f2b(float v){ return __float2bfloat16(v); }

// async global->LDS, 16B per lane; LDS dest = wave-uniform base + lane*16
__device__ __forceinline__ void gload16(const bf16* g, bf16* l) {
    __builtin_amdgcn_global_load_lds(
        (const __attribute__((address_space(1))) void*)g,
        (__attribute__((address_space(3))) void*)l, 16, 0, 0);
}

// ---------------------------------------------------------------- K0: repack wavelet + amp weights (transposed bf16)
__global__ __launch_bounds__(256) void repack_kernel(
    const float* __restrict__ wav,    // [NW][C][C] (w,c,o)
    const float* __restrict__ ampw,   // [C][C]     (c,o)
    bf16* __restrict__ WWT,           // [512][2048] : WWT[o][w*512+c]
    bf16* __restrict__ AWT)           // [512][512]  : AWT[o][c]
{
    int id = blockIdx.x * 256 + threadIdx.x;
    if (id < 512 * 2048) {
        int o = id >> 11, k = id & 2047;
        int w = k >> 9, c2 = k & 511;
        WWT[id] = f2b(wav[(w * 512 + c2) * 512 + o]);
    }
    if (id < 512 * 512) {
        int o = id >> 9, c = id & 511;
        AWT[id] = f2b(ampw[c * 512 + o]);
    }
}

// ---------------------------------------------------------------- K0b: cheby -> power-basis panel CCT[o][p*512+c] + bias0[o]
// trend_out = bias0 + x*(W1-3W3) + x^2*(2W2) + x^3*(4W3), bias0 = sum_c (W0-W2)
__global__ __launch_bounds__(64) void repack_cct_kernel(
    const float* __restrict__ cheby,  // [C][C][4] (c,o,d)
    bf16* __restrict__ CCT,           // [512][1536]
    float* __restrict__ bias0)        // [512]
{
    const int o = blockIdx.x, l = threadIdx.x;
    float bsum = 0.f;
    #pragma unroll
    for (int j = 0; j < 8; ++j) {
        int c = l + j * 64;
        float4 w = *(const float4*)&cheby[(size_t)c * 2048 + o * 4];
        bsum += w.x - w.z;
        CCT[(size_t)o * 1536 + c]        = f2b(w.y - 3.f * w.w);
        CCT[(size_t)o * 1536 + 512 + c]  = f2b(2.f * w.z);
        CCT[(size_t)o * 1536 + 1024 + c] = f2b(4.f * w.w);
    }
    #pragma unroll
    for (int off = 32; off >= 1; off >>= 1) bsum += __shfl_down(bsum, off);
    if (l == 0) bias0[o] = bsum;
}

// ---------------------------------------------------------------- K0c: LDS-tiled transpose w1[1024][512] -> w1T[512][1024]
__global__ __launch_bounds__(256) void transpose_w1_kernel(
    const float* __restrict__ w1, float* __restrict__ w1t)
{
    __shared__ float tile[32][33];
    const int bo = blockIdx.x, bj = blockIdx.y;
    const int tx = threadIdx.x & 31, ty = threadIdx.x >> 5;
    #pragma unroll
    for (int r = 0; r < 32; r += 8)
        tile[ty + r][tx] = w1[(size_t)(bj * 32 + ty + r) * 512 + bo * 32 + tx];
    __syncthreads();
    #pragma unroll
    for (int r = 0; r < 32; r += 8)
        w1t[(size_t)(bo * 32 + ty + r) * 1024 + bj * 32 + tx] = tile[tx][ty + r];
}

// ---------------------------------------------------------------- K1: causal MA + dwconv3 x3 + power basis + pools
__global__ __launch_bounds__(256) void decomp_kernel(
    const float* __restrict__ x,
    const float* __restrict__ tcw, const float* __restrict__ tcb,
    const float* __restrict__ scw, const float* __restrict__ scb,
    const float* __restrict__ lcw, const float* __restrict__ lcb,
    bf16* __restrict__ xt_pow,    // [M][1536] : [tanh | tanh^2 | tanh^3]
    bf16* __restrict__ sctx,      // [M][512]
    float* __restrict__ slope_part, float* __restrict__ value_part)
{
    const int c     = threadIdx.x * 2;          // channel pair
    const int chunk = blockIdx.x;               // 64 chunks
    const int b     = blockIdx.y;               // 16
    const int t0    = chunk * TCHUNK;
    const float* xb = x + (size_t)b * T_ * C_ + c;

    auto X = [&](int i) -> float2 {
        i = i < 0 ? 0 : (i > T_ - 1 ? T_ - 1 : i);
        return *(const float2*)&xb[(size_t)i * C_];
    };

    float w0t[2], w1t_[2], w2t[2], bt[2], w0s[2], w1s[2], w2s[2], bs[2], w0l[2], w1l[2], w2l[2], bl[2];
    #pragma unroll
    for (int e = 0; e < 2; ++e) {
        w0t[e]=tcw[(c+e)*3+0]; w1t_[e]=tcw[(c+e)*3+1]; w2t[e]=tcw[(c+e)*3+2]; bt[e]=tcb[c+e];
        w0s[e]=scw[(c+e)*3+0]; w1s[e]=scw[(c+e)*3+1]; w2s[e]=scw[(c+e)*3+2]; bs[e]=scb[c+e];
        w0l[e]=lcw[(c+e)*3+0]; w1l[e]=lcw[(c+e)*3+1]; w2l[e]=lcw[(c+e)*3+2]; bl[e]=lcb[c+e];
    }

    const float inv = 1.f / KWIN;
    int j0 = (t0 > 0) ? (t0 - 1) : 0;
    float S[2] = {0.f, 0.f};
    #pragma unroll
    for (int i = j0 - (KWIN - 1); i <= j0; ++i) { float2 v = X(i); S[0] += v.x; S[1] += v.y; }
    float trm[2], tr0[2], xm[2], x0v[2], sAcc[2] = {0.f,0.f}, vAcc[2] = {0.f,0.f};
    trm[0] = S[0] * inv; trm[1] = S[1] * inv;
    if (t0 > 0) {
        float2 a = X(t0), d = X(t0 - KWIN);
        S[0] += a.x - d.x; S[1] += a.y - d.y;
        tr0[0] = S[0] * inv; tr0[1] = S[1] * inv;
    } else { tr0[0] = trm[0]; tr0[1] = trm[1]; }
    { float2 v = X(t0 - 1); xm[0] = v.x; xm[1] = v.y; }
    { float2 v = X(t0);     x0v[0] = v.x; x0v[1] = v.y; }

    #pragma unroll
    for (int t = t0; t < t0 + TCHUNK; ++t) {
        float trp[2], xp[2];
        int tn = t + 1;
        if (tn <= T_ - 1) {
            float2 a = X(tn), d = X(tn - KWIN);
            S[0] += a.x - d.x; S[1] += a.y - d.y;
            trp[0] = S[0] * inv; trp[1] = S[1] * inv;
            xp[0] = a.x; xp[1] = a.y;
        } else {
            trp[0] = tr0[0]; trp[1] = tr0[1];
            xp[0] = x0v[0];  xp[1] = x0v[1];
        }
        union { bf16 h[2]; unsigned u; } u1, u2, u3, usc;
        #pragma unroll
        for (int e = 0; e < 2; ++e) {
            float tctx = w0t[e]*trm[e] + w1t_[e]*tr0[e] + w2t[e]*trp[e] + bt[e];
            float sm = xm[e]-trm[e], s0 = x0v[e]-tr0[e], sp = xp[e]-trp[e];
            float sv = w0s[e]*sm + w1s[e]*s0 + w2s[e]*sp + bs[e];
            float sl = w0l[e]*trm[e] + w1l[e]*tr0[e] + w2l[e]*trp[e] + bl[e];
            sAcc[e] += sl; vAcc[e] += tr0[e];
            float th = tanhf(tctx);
            u1.h[e] = f2b(th); u2.h[e] = f2b(th * th); u3.h[e] = f2b(th * th * th);
            usc.h[e] = f2b(sv);
            trm[e] = tr0[e]; tr0[e] = trp[e]; xm[e] = x0v[e]; x0v[e] = xp[e];
        }
        size_t m = (size_t)b * T_ + t;
        size_t prow = m * 1536 + c;
        *(unsigned*)&xt_pow[prow]        = u1.u;
        *(unsigned*)&xt_pow[prow + 512]  = u2.u;
        *(unsigned*)&xt_pow[prow + 1024] = u3.u;
        *(unsigned*)&sctx[m * C_ + c]    = usc.u;
    }
    int pidx = (chunk * B_ + b) * C_ + c;
    *(float2*)&slope_part[pidx] = make_float2(sAcc[0], sAcc[1]);
    *(float2*)&value_part[pidx] = make_float2(vAcc[0], vAcc[1]);
}

// ---------------------------------------------------------------- K2a: pool reduce -> pc[16][1024]
__global__ __launch_bounds__(256) void pool_kernel(
    const float* __restrict__ slope_part, const float* __restrict__ value_part,
    float* __restrict__ pc)
{
    int idx = blockIdx.x * 256 + threadIdx.x;   // 16384
    int b = idx >> 10, j = idx & 1023;
    int c = j & 511;
    const float* src = (j < 512) ? slope_part : value_part;
    float s = 0.f;
    #pragma unroll 8
    for (int ch = 0; ch < NCHUNK; ++ch) s += src[(ch * B_ + b) * C_ + c];
    pc[idx] = s * (1.f / T_);
}

// ---------------------------------------------------------------- K2b: h = silu(pc @ w1 + b1); 1 block per o
__global__ __launch_bounds__(256) void hyper1_kernel(
    const float* __restrict__ pc, const float* __restrict__ w1t,
    const float* __restrict__ b1, float* __restrict__ h)
{
    const int o = blockIdx.x, t = threadIdx.x;
    const float4 w = *(const float4*)&w1t[(size_t)o * 1024 + t * 4];
    float acc[16];
    #pragma unroll
    for (int b = 0; b < 16; ++b) {
        float4 p = *(const float4*)&pc[(size_t)b * 1024 + t * 4];
        acc[b] = w.x * p.x + w.y * p.y + w.z * p.z + w.w * p.w;
    }
    #pragma unroll
    for (int off = 32; off >= 1; off >>= 1)
        #pragma unroll
        for (int b = 0; b < 16; ++b) acc[b] += __shfl_down(acc[b], off);
    __shared__ float red[4][16];
    int lane = t & 63, wv = t >> 6;
    if (lane == 0)
        #pragma unroll
        for (int b = 0; b < 16; ++b) red[wv][b] = acc[b];
    __syncthreads();
    if (t < 16) {
        float s = red[0][t] + red[1][t] + red[2][t] + red[3][t] + b1[o];
        h[(size_t)t * 512 + o] = s / (1.f + expf(-s));
    }
}

// ---------------------------------------------------------------- K2c: params -> dyn_a, dyn_b
__global__ __launch_bounds__(128) void hyper2_kernel(
    const float* __restrict__ h, const float* __restrict__ w2,
    const float* __restrict__ b2, float* __restrict__ dyn_a, float* __restrict__ dyn_b)
{
    __shared__ float pp[16][8];
    const int t = threadIdx.x, b = t >> 3, o = t & 7;
    float acc = b2[o];
    #pragma unroll 4
    for (int j = 0; j < 512; ++j) acc += h[(size_t)b * 512 + j] * w2[j * 8 + o];
    pp[b][o] = acc;
    __syncthreads();
    if (t < 64) {
        int bb = t >> 2, w = t & 3;
        float pa = pp[bb][2 * w], pb = pp[bb][2 * w + 1];
        float sp = fmaxf(pa, 0.f) + log1pf(expf(-fabsf(pa)));
        dyn_a[bb * NW_ + w] = sp + 0.01f;
        dyn_b[bb * NW_ + w] = (1.f / (1.f + expf(-pb))) * (float)T_;
    }
}

// ---------------------------------------------------------------- K2d: psi[m][w] Ricker wavelet
__global__ __launch_bounds__(256) void psi_kernel(
    const float* __restrict__ dyn_a, const float* __restrict__ dyn_b,
    float* __restrict__ psi)
{
    int idx = blockIdx.x * 256 + threadIdx.x;
    int w = idx & 3, m = idx >> 2;
    int b = m >> 10, t = m & 1023;
    float z = ((float)t - dyn_b[b * 4 + w]) / dyn_a[b * 4 + w];
    float z2 = z * z;
    psi[idx] = (1.f - z2) * expf(-0.5f * z2);
}

// ---------------------------------------------------------------- Fused big GEMM
// logical mode0: tout = xt_pow[M][1536] @ CCT^T  (pure gload_lds A)
// logical mode1: sout = (psi-scaled sctx)[M][2048] @ WWT^T (reg-staged A)
// XCD-bijective swizzle interleaves modes + keeps n-blocks of one m-panel adjacent.
__global__ __launch_bounds__(256, 4) void gemm_big_kernel(
    const bf16* __restrict__ xt_pow, const bf16* __restrict__ sctxg,
    const bf16* __restrict__ CCT,  const bf16* __restrict__ WWT,
    const float* __restrict__ psi, const float* __restrict__ bias0,
    bf16* __restrict__ tout, bf16* __restrict__ sout)
{
    __shared__ bf16 lA[128 * 64];   // 16 KB
    __shared__ bf16 lB[128 * 64];   // 16 KB

    const int lin  = blockIdx.x + (blockIdx.y << 2) + (blockIdx.z << 9);  // grid (4,128,2)
    const int swz  = ((lin & 7) << 7) + (lin >> 3);   // bijective, 1024 % 8 == 0
    const int nb   = swz & 3;
    const int mode = (swz >> 2) & 1;
    const int mb   = swz >> 3;
    const int m0 = mb << 7, n0 = nb << 7;

    const int K = mode ? 2048 : 1536;
    const bf16* BTm = mode ? WWT : CCT;
    bf16* Cmat = mode ? sout : tout;

    const int tid = threadIdx.x;
    const int lane = tid & 63, wv = tid >> 6;
    const int wr = wv >> 1, wc = wv & 1;
    const int r16 = lane & 15, g = lane >> 4;
    const int sr8 = lane >> 3, sslot = lane & 7;

    // mode1 reg-staging ids: 2 threads per row, 32 elems each
    const int arow = tid >> 1, hh = tid & 1;
    float4 p4 = make_float4(0.f, 0.f, 0.f, 0.f);
    if (mode) p4 = *(const float4*)&psi[(size_t)(m0 + arow) * 4];

    f4v acc[4][4];
    #pragma unroll
    for (int i = 0; i < 4; ++i)
        #pragma unroll
        for (int j = 0; j < 4; ++j) acc[i][j] = (f4v)0.f;

    const int nK = K >> 6;
    for (int kt = 0; kt < nK; ++kt) {
        const int k0 = kt << 6;

        // ---- B stage (async gload_lds, pre-swizzled source) ----
        #pragma unroll
        for (int i2 = 0; i2 < 4; ++i2) {
            int r = wv * 32 + i2 * 8 + sr8;
            int ls = sslot ^ (r & 7);
            gload16(BTm + (size_t)(n0 + r) * K + k0 + ls * 8, &lB[(wv * 32 + i2 * 8) * 64]);
        }

        if (mode == 0) {
            // ---- A stage: plain copy from xt_pow (row stride 1536) ----
            #pragma unroll
            for (int i2 = 0; i2 < 4; ++i2) {
                int r = wv * 32 + i2 * 8 + sr8;
                int ls = sslot ^ (r & 7);
                gload16(xt_pow + (size_t)(m0 + r) * 1536 + k0 + ls * 8, &lA[(wv * 32 + i2 * 8) * 64]);
            }
            __syncthreads();    // drains vmcnt -> tiles resident
        } else {
            // ---- A stage: reg-load sctx, psi-scale, swizzled ds_write ----
            const int wsel = k0 >> 9;
            const float sc = wsel == 0 ? p4.x : wsel == 1 ? p4.y : wsel == 2 ? p4.z : p4.w;
            s8v av[4];
            const bf16* srcA = sctxg + (size_t)(m0 + arow) * 512 + (k0 & 511) + hh * 32;
            #pragma unroll
            for (int j2 = 0; j2 < 4; ++j2) av[j2] = *(const s8v*)(srcA + j2 * 8);
            __syncthreads();    // prev-iter LDS reads done; B vmcnt drained
            #pragma unroll
            for (int j2 = 0; j2 < 4; ++j2) {
                s8v ov;
                #pragma unroll
                for (int e = 0; e < 8; ++e)
                    ((bf16*)&ov)[e] = f2b(b2f(((const bf16*)&av[j2])[e]) * sc);
                int q = hh * 4 + j2;
                *(s8v*)&lA[arow * 64 + ((q ^ (arow & 7)) << 3)] = ov;
            }
            __syncthreads();    // ds_writes visible
        }

        // ---- compute: 2 mfma-K steps of 32 ----
        #pragma unroll
        for (int ks = 0; ks < 2; ++ks) {
            s8v afr[4], bfr[4];
            #pragma unroll
            for (int i = 0; i < 4; ++i) {
                int ar = wr * 64 + i * 16 + r16;
                afr[i] = *(const s8v*)((const char*)lA + ar * 128 + (((ks * 4 + g) ^ (ar & 7)) << 4));
            }
            #pragma unroll
            for (int j = 0; j < 4; ++j) {
                int br = wc * 64 + j * 16 + r16;
                bfr[j] = *(const s8v*)((const char*)lB + br * 128 + (((ks * 4 + g) ^ (br & 7)) << 4));
            }
            #pragma unroll
            for (int i = 0; i < 4; ++i)
                #pragma unroll
                for (int j = 0; j < 4; ++j)
                    acc[i][j] = __builtin_amdgcn_mfma_f32_16x16x32_bf16(afr[i], bfr[j], acc[i][j], 0, 0, 0);
        }
        __syncthreads();        // reads done before next-iter staging writes
    }

    // ---- C write (D: col=lane&15, row=(lane>>4)*4+r), + bias for mode0 ----
    #pragma unroll
    for (int i = 0; i < 4; ++i)
        #pragma unroll
        for (int j = 0; j < 4; ++j) {
            int cc = n0 + wc * 64 + j * 16 + r16;
            float bb = (mode == 0) ? bias0[cc] : 0.f;
            #pragma unroll
            for (int r = 0; r < 4; ++r) {
                int rr = m0 + wr * 64 + i * 16 + g * 4 + r;
                Cmat[(size_t)rr * 512 + cc] = f2b(acc[i][j][r] + bb);
            }
        }
}

// ---------------------------------------------------------------- GEMM2: ampin = tout @ AWT^T, K=512, both sides gload_lds
__global__ __launch_bounds__(256, 3) void gemm2_kernel(
    const bf16* __restrict__ Ag, const bf16* __restrict__ Bg,
    bf16* __restrict__ Cmat)
{
    __shared__ bf16 lA[128 * 64];
    __shared__ bf16 lB[128 * 64];

    const int tid = threadIdx.x;
    const int m0 = blockIdx.y * 128, n0 = blockIdx.x * 128;
    const int lane = tid & 63, wv = tid >> 6;
    const int wr = wv >> 1, wc = wv & 1;
    const int r16 = lane & 15, g = lane >> 4;
    const int srow = wv * 32 + (lane >> 3);
    const int sslot = lane & 7;

    f4v acc[4][4];
    #pragma unroll
    for (int i = 0; i < 4; ++i)
        #pragma unroll
        for (int j = 0; j < 4; ++j) acc[i][j] = (f4v)0.f;

    for (int kt = 0; kt < 8; ++kt) {
        const int k0 = kt << 6;
        #pragma unroll
        for (int i2 = 0; i2 < 4; ++i2) {
            int r = srow + i2 * 8;
            int ls = sslot ^ (r & 7);
            gload16(Ag + (size_t)(m0 + r) * 512 + k0 + ls * 8, &lA[(wv * 32 + i2 * 8) * 64]);
            gload16(Bg + (size_t)(n0 + r) * 512 + k0 + ls * 8, &lB[(wv * 32 + i2 * 8) * 64]);
        }
        __syncthreads();
        #pragma unroll
        for (int ks = 0; ks < 2; ++ks) {
            s8v afr[4], bfr[4];
            #pragma unroll
            for (int i = 0; i < 4; ++i) {
                int ar = wr * 64 + i * 16 + r16;
                afr[i] = *(const s8v*)((const char*)lA + ar * 128 + (((ks * 4 + g) ^ (ar & 7)) << 4));
            }
            #pragma unroll
            for (int j = 0; j < 4; ++j) {
                int br = wc * 64 + j * 16 + r16;
                bfr[j] = *(const s8v*)((const char*)lB + br * 128 + (((ks * 4 + g) ^ (br & 7)) << 4));
            }
            #pragma unroll
            for (int i = 0; i < 4; ++i)
                #pragma unroll
                for (int j = 0; j < 4; ++j)
                    acc[i][j] = __builtin_amdgcn_mfma_f32_16x16x32_bf16(afr[i], bfr[j], acc[i][j], 0, 0, 0);
        }
        __syncthreads();
    }
    #pragma unroll
    for (int i = 0; i < 4; ++i)
        #pragma unroll
        for (int j = 0; j < 4; ++j)
            #pragma unroll
            for (int r = 0; r < 4; ++r) {
                int rr = m0 + wr * 64 + i * 16 + g * 4 + r;
                int cc = n0 + wc * 64 + j * 16 + r16;
                Cmat[(size_t)rr * 512 + cc] = f2b(acc[i][j][r]);
            }
}

// ---------------------------------------------------------------- K6: amp gate + residual + LayerNorm
__global__ __launch_bounds__(256) void epilogue_kernel(
    const float* __restrict__ x,   const bf16* __restrict__ tout,
    const bf16* __restrict__ sout, const bf16* __restrict__ ampin,
    const float* __restrict__ ampb, const float* __restrict__ gamma,
    const float* __restrict__ beta, float* __restrict__ out)
{
    __shared__ float red[8];
    const int m = blockIdx.x, tid = threadIdx.x;
    const size_t base = (size_t)m * 512;

    float y[2];
    #pragma unroll
    for (int q = 0; q < 2; ++q) {
        int c = tid + q * 256;
        float to = b2f(tout[base + c]);
        float so = b2f(sout[base + c]);
        float ai = b2f(ampin[base + c]) + ampb[c];
        float amp = 2.f / (1.f + expf(-ai));
        y[q] = to + so * amp + x[base + c];
    }
    float s = y[0] + y[1], sq = y[0] * y[0] + y[1] * y[1];
    #pragma unroll
    for (int off = 32; off >= 1; off >>= 1) {
        s  += __shfl_down(s, off);
        sq += __shfl_down(sq, off);
    }
    int lane = tid & 63, wv = tid >> 6;
    if (lane == 0) { red[wv * 2] = s; red[wv * 2 + 1] = sq; }
    __syncthreads();
    if (tid == 0) {
        float ts = 0.f, tq = 0.f;
        #pragma unroll
        for (int i = 0; i < 4; ++i) { ts += red[i * 2]; tq += red[i * 2 + 1]; }
        red[0] = ts; red[1] = tq;
    }
    __syncthreads();
    float mu  = red[0] * (1.f / 512.f);
    float var = red[1] * (1.f / 512.f) - mu * mu;
    float rstd = rsqrtf(var + 1e-5f);
    #pragma unroll
    for (int q = 0; q < 2; ++q) {
        int c = tid + q * 256;
        out[base + c] = (y[q] - mu) * rstd * gamma[c] + beta[c];
    }
}

// ----------------------------------------------------------------
extern "C" void kernel_launch(void* const* d_in, const int* in_sizes, int n_in,
                              void* d_out, int out_size, void* d_ws, size_t ws_size,
                              hipStream_t stream)
{
    const float* x     = (const float*)d_in[0];
    const float* tcw   = (const float*)d_in[1];
    const float* tcb   = (const float*)d_in[2];
    const float* scw   = (const float*)d_in[3];
    const float* scb   = (const float*)d_in[4];
    const float* lcw   = (const float*)d_in[5];
    const float* lcb   = (const float*)d_in[6];
    const float* cheby = (const float*)d_in[7];
    const float* hw1   = (const float*)d_in[8];
    const float* hb1   = (const float*)d_in[9];
    const float* hw2   = (const float*)d_in[10];
    const float* hb2   = (const float*)d_in[11];
    const float* ampw  = (const float*)d_in[12];
    const float* ampb  = (const float*)d_in[13];
    const float* wav   = (const float*)d_in[14];
    const float* lng   = (const float*)d_in[15];
    const float* lnb   = (const float*)d_in[16];
    float* out = (float*)d_out;

    char* ws = (char*)d_ws;
    size_t off = 0;
    auto alloc = [&](size_t bytes) -> char* {
        char* p = ws + off;
        off += (bytes + 255) & ~(size_t)255;
        return p;
    };
    bf16*  xt_pow     = (bf16*)alloc((size_t)M_ * 1536 * 2);
    bf16*  sctx       = (bf16*)alloc((size_t)M_ * 512 * 2);
    bf16*  tout       = (bf16*)alloc((size_t)M_ * 512 * 2);
    bf16*  sout       = (bf16*)alloc((size_t)M_ * 512 * 2);
    bf16*  ampin      = (bf16*)alloc((size_t)M_ * 512 * 2);
    bf16*  CCT        = (bf16*)alloc((size_t)512 * 1536 * 2);
    bf16*  WWT        = (bf16*)alloc((size_t)512 * 2048 * 2);
    bf16*  AWT        = (bf16*)alloc((size_t)512 * 512 * 2);
    float* W1T        = (float*)alloc((size_t)512 * 1024 * 4);
    float* bias0      = (float*)alloc(512 * 4);
    float* slope_part = (float*)alloc((size_t)NCHUNK * B_ * C_ * 4);
    float* value_part = (float*)alloc((size_t)NCHUNK * B_ * C_ * 4);
    float* pc         = (float*)alloc(B_ * 1024 * 4);
    float* hbuf       = (float*)alloc(B_ * C_ * 4);
    float* dyn_a      = (float*)alloc(B_ * NW_ * 4);
    float* dyn_b      = (float*)alloc(B_ * NW_ * 4);
    float* psi        = (float*)alloc((size_t)M_ * NW_ * 4);

    repack_kernel<<<4096, 256, 0, stream>>>(wav, ampw, WWT, AWT);
    repack_cct_kernel<<<512, 64, 0, stream>>>(cheby, CCT, bias0);
    transpose_w1_kernel<<<dim3(16, 32), 256, 0, stream>>>(hw1, W1T);
    decomp_kernel<<<dim3(NCHUNK, B_), 256, 0, stream>>>(x, tcw, tcb, scw, scb, lcw, lcb,
                                                        xt_pow, sctx, slope_part, value_part);
    pool_kernel<<<64, 256, 0, stream>>>(slope_part, value_part, pc);
    hyper1_kernel<<<512, 256, 0, stream>>>(pc, W1T, hb1, hbuf);
    hyper2_kernel<<<1, 128, 0, stream>>>(hbuf, hw2, hb2, dyn_a, dyn_b);
    psi_kernel<<<256, 256, 0, stream>>>(dyn_a, dyn_b, psi);
    gemm_big_kernel<<<dim3(4, 128, 2), 256, 0, stream>>>(xt_pow, sctx, CCT, WWT, psi, bias0, tout, sout);
    gemm2_kernel<<<dim3(4, 128), 256, 0, stream>>>(tout, AWT, ampin);
    epilogue_kernel<<<16384, 256, 0, stream>>>(x, tout, sout, ampin, ampb, lng, lnb, out);
}